// Round 9
// baseline (117.457 us; speedup 1.0000x reference)
//
#include <hip/hip_runtime.h>
#include <hip/hip_bf16.h>

#define HWA 4096
#define CCH 256
#define NBATCH 4
#define QB 64
#define KBT 128
#define NTILES (HWA / KBT)   // 32
// q is pre-scaled by log2(e) in qkvgemm, so exp(s-16) == exp2(s' - SMAXL2)
#define SMAXL2 23.083120654223414f
#define LOG2E  1.4426950408889634f

typedef __attribute__((ext_vector_type(8))) short bf16x8;
typedef __attribute__((ext_vector_type(4))) float f32x4;

__device__ __forceinline__ unsigned short f2bf(float f) {
    union { float f; unsigned u; } a; a.f = f;
    unsigned r = a.u + 0x7FFFu + ((a.u >> 16) & 1u);
    return (unsigned short)(r >> 16);
}
__device__ __forceinline__ float bf2f(unsigned short h) {
    union { unsigned u; float f; } a; a.u = ((unsigned)h) << 16;
    return a.f;
}
// raw barrier: drain LDS ops only, keep global prefetch (vmcnt) in flight
__device__ __forceinline__ void bar_lds() {
    asm volatile("s_waitcnt lgkmcnt(0)" ::: "memory");
    __builtin_amdgcn_s_barrier();
}

// ---------------- Stage 0: pack W into A-fragment-ordered hi/lo bf16 ----------------
__global__ __launch_bounds__(256) void wprep_kernel(
    const float* __restrict__ Wq, const float* __restrict__ bq,
    const float* __restrict__ Wk, const float* __restrict__ bk,
    const float* __restrict__ Wv, const float* __restrict__ bv,
    unsigned short* __restrict__ whi, unsigned short* __restrict__ wlo,
    float* __restrict__ bias_all)
{
    const int ot = blockIdx.x;
    const int t = threadIdx.x;
    const int lane = t & 63;
    const int l15 = lane & 15, g = lane >> 4;
    const int och = ot * 16 + l15;
    #pragma unroll
    for (int pass = 0; pass < 2; ++pass) {
        const int kf = (t >> 6) + 4 * pass;
        unsigned short h8[8], l8[8];
        #pragma unroll
        for (int j = 0; j < 8; ++j) {
            int c = 32 * kf + g * 8 + j;
            float v;
            if (och < 32)      v = Wq[och * CCH + c];
            else if (och < 64) v = Wk[(och - 32) * CCH + c];
            else               v = Wv[(och - 64) * CCH + c];
            unsigned short hb = f2bf(v);
            h8[j] = hb;
            l8[j] = f2bf(v - bf2f(hb));
        }
        size_t base = ((size_t)(ot * 8 + kf) * 64 + lane) * 8;
        *(bf16x8*)(whi + base) = *(bf16x8*)h8;
        *(bf16x8*)(wlo + base) = *(bf16x8*)l8;
    }
    if (ot == 0) {
        for (int i = t; i < 320; i += 256)
            bias_all[i] = (i < 32) ? bq[i] : (i < 64) ? bk[i - 32] : bv[i - 64];
    }
}

// ---------------- Stage 1: MFMA projection GEMM ----------------
// Grid 512 (XCD-swizzled), 4 waves, 2 blocks/CU; q outputs pre-scaled by log2e.
__global__ __launch_bounds__(256) void qkvgemm_kernel(
    const float* __restrict__ x,
    const unsigned short* __restrict__ whi, const unsigned short* __restrict__ wlo,
    const float* __restrict__ bias_all,
    unsigned short* __restrict__ qhi, unsigned short* __restrict__ qlo,
    unsigned short* __restrict__ khi, unsigned short* __restrict__ klo,
    unsigned short* __restrict__ vb)
{
    const int t = threadIdx.x;
    const int w = t >> 6, l = t & 63, l15 = l & 15, g = l >> 4;
    const int b = blockIdx.x;
    const int logical = (b & 7) * 64 + (b >> 3);
    const int n    = logical >> 7;
    const int rem  = logical & 127;
    const int cb   = rem >> 1;
    const int half = rem & 1;
    const int col = cb * 64 + w * 16 + l15;

    bf16x8 Bh[8], Bl[8];
    #pragma unroll
    for (int kf = 0; kf < 8; ++kf) {
        unsigned short hh[8], ll[8];
        #pragma unroll
        for (int j = 0; j < 8; ++j) {
            float v = x[((size_t)(n * CCH + 32 * kf + g * 8 + j)) * HWA + col];
            unsigned short hb = f2bf(v);
            hh[j] = hb;
            ll[j] = f2bf(v - bf2f(hb));
        }
        Bh[kf] = *(bf16x8*)hh;
        Bl[kf] = *(bf16x8*)ll;
    }

    const f32x4 zero4 = {0.f, 0.f, 0.f, 0.f};
    for (int ot = half * 10; ot < half * 10 + 10; ++ot) {
        f32x4 acc = zero4;
        #pragma unroll
        for (int kf = 0; kf < 8; ++kf) {
            size_t base = ((size_t)(ot * 8 + kf) * 64 + l) * 8;
            bf16x8 Ah = *(const bf16x8*)(whi + base);
            bf16x8 Al = *(const bf16x8*)(wlo + base);
            acc = __builtin_amdgcn_mfma_f32_16x16x32_bf16(Ah, Bh[kf], acc, 0, 0, 0);
            acc = __builtin_amdgcn_mfma_f32_16x16x32_bf16(Ah, Bl[kf], acc, 0, 0, 0);
            acc = __builtin_amdgcn_mfma_f32_16x16x32_bf16(Al, Bh[kf], acc, 0, 0, 0);
        }
        f32x4 bia = *(const f32x4*)&bias_all[ot * 16 + 4 * g];
        float vv[4];
        #pragma unroll
        for (int r = 0; r < 4; ++r) vv[r] = acc[r] + bia[r];

        if (ot < 4) {
            if (ot < 2) {               // q rows: fold log2e for exp2-domain softmax
                #pragma unroll
                for (int r = 0; r < 4; ++r) vv[r] *= LOG2E;
            }
            unsigned short h4[4], l4[4];
            #pragma unroll
            for (int r = 0; r < 4; ++r) {
                unsigned short hb = f2bf(vv[r]);
                h4[r] = hb;
                l4[r] = f2bf(vv[r] - bf2f(hb));
            }
            unsigned short* hp = (ot < 2) ? qhi : khi;
            unsigned short* lp = (ot < 2) ? qlo : klo;
            size_t base = ((size_t)(n * HWA + col)) * 32 + (ot & 1) * 16 + 4 * g;
            *(ushort4*)(hp + base) = *(ushort4*)h4;
            *(ushort4*)(lp + base) = *(ushort4*)l4;
        } else {
            #pragma unroll
            for (int r = 0; r < 4; ++r)
                vb[((size_t)(n * CCH + ot * 16 - 64 + 4 * g + r)) * HWA + col] = f2bf(vv[r]);
        }
    }
}

// ---------------- Stage 2: static-max MFMA flash attention ----------------
// Grid 256 (XCD-swizzled), 8 waves, QB=64. K/V loads are explicit inline-asm
// global_load_dwordx4 into register double-buffers (scheduler cannot sink
// them); one vmcnt(0) per tile waits loads issued a FULL iteration earlier.
// expPack(t+1) interleaved with PV(t) so softmax VALU hides under MFMA.
__global__ __launch_bounds__(512, 2) void attn_kernel(
    const unsigned short* __restrict__ qhi, const unsigned short* __restrict__ qlo,
    const unsigned short* __restrict__ khi, const unsigned short* __restrict__ klo,
    const unsigned short* __restrict__ vb,  const float* __restrict__ x,
    const float* __restrict__ gamma_p, float* __restrict__ out)
{
    __shared__ unsigned short P_lds[2][8192];   // 2 x 16 KB, A-frag order
    __shared__ float lsum_lds[64][9];
    __shared__ float out_lds[16][265];

    const int tid = threadIdx.x;
    const int w = tid >> 6;
    const int l = tid & 63;
    const int l15 = l & 15;
    const int g = l >> 4;

    const int bid = blockIdx.x;
    const int logical = (bid & 7) * 32 + (bid >> 3);
    const int n  = logical >> 6;
    const int qb = logical & 63;
    const int q0 = qb * QB;

    // Q fragments (B operand)
    bf16x8 Qh[4], Ql[4];
    #pragma unroll
    for (int nt = 0; nt < 4; ++nt) {
        size_t a = ((size_t)(n * HWA + q0 + 16 * nt + l15)) * 32 + g * 8;
        Qh[nt] = *(const bf16x8*)(qhi + a);
        Ql[nt] = *(const bf16x8*)(qlo + a);
    }

    // per-lane base addresses
    const unsigned short* kbase  = khi + ((size_t)(n * HWA + 16 * w + l15)) * 32 + g * 8;
    const unsigned short* kbasel = klo + ((size_t)(n * HWA + 16 * w + l15)) * 32 + g * 8;
    const unsigned short* vbase0 = vb + ((size_t)(n * CCH + 32 * w + l15)) * HWA + g * 8;
    const unsigned short* vbase1 = vbase0 + 16 * HWA;

    f32x4 acc[4][2] = {};
    f32x4 s_acc[4];
    float lsum[4] = {0.f, 0.f, 0.f, 0.f};
    const f32x4 zero4 = {0.f, 0.f, 0.f, 0.f};

    // register double buffers (asm-pinned)
    bf16x8 KhA, KlA, KhB, KlB;
    bf16x8 VA[2][4], VB[2][4];

    // running prefetch pointers: K(t+2), V(t+1) at body t
    const unsigned short* kph = kbase  + (size_t)2 * KBT * 32;
    const unsigned short* kpl = kbasel + (size_t)2 * KBT * 32;
    const unsigned short* vp0 = vbase0 + KBT;
    const unsigned short* vp1 = vbase1 + KBT;

    // ---- prologue: QK(0), load K(1)->A V(0)->A, expPack(0) ----
    {
        bf16x8 k0h = *(const bf16x8*)kbase;
        bf16x8 k0l = *(const bf16x8*)kbasel;
        #pragma unroll
        for (int nt = 0; nt < 4; ++nt) {
            f32x4 sa = __builtin_amdgcn_mfma_f32_16x16x32_bf16(k0h, Qh[nt], zero4, 0, 0, 0);
            sa = __builtin_amdgcn_mfma_f32_16x16x32_bf16(k0h, Ql[nt], sa, 0, 0, 0);
            sa = __builtin_amdgcn_mfma_f32_16x16x32_bf16(k0l, Qh[nt], sa, 0, 0, 0);
            s_acc[nt] = sa;
        }
    }
    KhA = *(const bf16x8*)(kbase + (size_t)KBT * 32);
    KlA = *(const bf16x8*)(kbasel + (size_t)KBT * 32);
    #pragma unroll
    for (int s = 0; s < 4; ++s) {
        VA[0][s] = *(const bf16x8*)(vbase0 + 32 * s);
        VA[1][s] = *(const bf16x8*)(vbase1 + 32 * s);
    }
    // expPack(0) -> buf0
    #pragma unroll
    for (int nt = 0; nt < 4; ++nt) {
        float e0 = __builtin_amdgcn_exp2f(s_acc[nt][0] - SMAXL2);
        float e1 = __builtin_amdgcn_exp2f(s_acc[nt][1] - SMAXL2);
        float e2 = __builtin_amdgcn_exp2f(s_acc[nt][2] - SMAXL2);
        float e3 = __builtin_amdgcn_exp2f(s_acc[nt][3] - SMAXL2);
        lsum[nt] += (e0 + e1) + (e2 + e3);
        __hip_bfloat162 b01 = __float22bfloat162_rn(make_float2(e0, e1));
        __hip_bfloat162 b23 = __float22bfloat162_rn(make_float2(e2, e3));
        char* pbp = (char*)P_lds + nt * 4096 + (w >> 1) * 1024 +
                    ((2 * (w & 1) + (g >> 1)) * 16 + l15) * 16 + (g & 1) * 8;
        *(uint2*)pbp = make_uint2(*(unsigned*)&b01, *(unsigned*)&b23);
    }
    bar_lds();                       // P(0) visible

    // ---- body: {wait loads; issue K(t+2),V(t+1); QK(t+1); PV(t)||expPack(t+1)} ----
    auto body = [&](int t, int pb, bf16x8& KcH, bf16x8& KcL, bf16x8 (&Vcur)[2][4],
                    bf16x8& KnH, bf16x8& KnL, bf16x8 (&Vnxt)[2][4]) {
        asm volatile("s_waitcnt vmcnt(0)" ::: "memory");   // K(t+1),V(t) arrived
        __builtin_amdgcn_sched_barrier(0);
        if (t + 2 < NTILES) {
            asm volatile("global_load_dwordx4 %0, %1, off" : "=v"(KnH) : "v"(kph));
            asm volatile("global_load_dwordx4 %0, %1, off" : "=v"(KnL) : "v"(kpl));
        }
        asm volatile("global_load_dwordx4 %0, %1, off"            : "=v"(Vnxt[0][0]) : "v"(vp0));
        asm volatile("global_load_dwordx4 %0, %1, off offset:64"  : "=v"(Vnxt[0][1]) : "v"(vp0));
        asm volatile("global_load_dwordx4 %0, %1, off offset:128" : "=v"(Vnxt[0][2]) : "v"(vp0));
        asm volatile("global_load_dwordx4 %0, %1, off offset:192" : "=v"(Vnxt[0][3]) : "v"(vp0));
        asm volatile("global_load_dwordx4 %0, %1, off"            : "=v"(Vnxt[1][0]) : "v"(vp1));
        asm volatile("global_load_dwordx4 %0, %1, off offset:64"  : "=v"(Vnxt[1][1]) : "v"(vp1));
        asm volatile("global_load_dwordx4 %0, %1, off offset:128" : "=v"(Vnxt[1][2]) : "v"(vp1));
        asm volatile("global_load_dwordx4 %0, %1, off offset:192" : "=v"(Vnxt[1][3]) : "v"(vp1));
        kph += (size_t)KBT * 32; kpl += (size_t)KBT * 32;
        vp0 += KBT; vp1 += KBT;

        __builtin_amdgcn_s_setprio(1);
        // QK(t+1)
        #pragma unroll
        for (int nt = 0; nt < 4; ++nt) {
            f32x4 sa = __builtin_amdgcn_mfma_f32_16x16x32_bf16(KcH, Qh[nt], zero4, 0, 0, 0);
            sa = __builtin_amdgcn_mfma_f32_16x16x32_bf16(KcH, Ql[nt], sa, 0, 0, 0);
            sa = __builtin_amdgcn_mfma_f32_16x16x32_bf16(KcL, Qh[nt], sa, 0, 0, 0);
            s_acc[nt] = sa;
        }
        // PV(t) interleaved with expPack(t+1): per s-slot, 8 MFMA + exp of nt=s
        const char* rdb = (const char*)P_lds + pb * 16384;
        char* wrb = (char*)P_lds + (pb ^ 1) * 16384;
        #pragma unroll
        for (int s = 0; s < 4; ++s) {
            bf16x8 Af[4];
            #pragma unroll
            for (int m = 0; m < 4; ++m)
                Af[m] = *(const bf16x8*)(rdb + (m * 4 + s) * 1024 + l * 16);
            #pragma unroll
            for (int m = 0; m < 4; ++m)
                #pragma unroll
                for (int ct = 0; ct < 2; ++ct)
                    acc[m][ct] = __builtin_amdgcn_mfma_f32_16x16x32_bf16(
                        Af[m], Vcur[ct][s], acc[m][ct], 0, 0, 0);
            // softmax slice nt=s (VALU, hides under the MFMA pipe)
            float e0 = __builtin_amdgcn_exp2f(s_acc[s][0] - SMAXL2);
            float e1 = __builtin_amdgcn_exp2f(s_acc[s][1] - SMAXL2);
            float e2 = __builtin_amdgcn_exp2f(s_acc[s][2] - SMAXL2);
            float e3 = __builtin_amdgcn_exp2f(s_acc[s][3] - SMAXL2);
            lsum[s] += (e0 + e1) + (e2 + e3);
            __hip_bfloat162 b01 = __float22bfloat162_rn(make_float2(e0, e1));
            __hip_bfloat162 b23 = __float22bfloat162_rn(make_float2(e2, e3));
            char* pbp = wrb + s * 4096 + (w >> 1) * 1024 +
                        ((2 * (w & 1) + (g >> 1)) * 16 + l15) * 16 + (g & 1) * 8;
            *(uint2*)pbp = make_uint2(*(unsigned*)&b01, *(unsigned*)&b23);
        }
        __builtin_amdgcn_s_setprio(0);
        bar_lds();                   // P(t+1) visible / buf[t&1] reads done
    };

    for (int tt = 0; tt + 1 < NTILES; tt += 2) {
        body(tt, 0, KhA, KlA, VA, KhB, KlB, VB);
        if (tt + 2 < NTILES) body(tt + 1, 1, KhB, KlB, VB, KhA, KlA, VA);
    }

    // ---- epilogue: PV(31) with VB, buf1 ----
    asm volatile("s_waitcnt vmcnt(0)" ::: "memory");
    __builtin_amdgcn_sched_barrier(0);
    __builtin_amdgcn_s_setprio(1);
    #pragma unroll
    for (int s = 0; s < 4; ++s) {
        bf16x8 Af[4];
        #pragma unroll
        for (int m = 0; m < 4; ++m)
            Af[m] = *(const bf16x8*)((const char*)P_lds + 16384 +
                                     (m * 4 + s) * 1024 + l * 16);
        #pragma unroll
        for (int m = 0; m < 4; ++m)
            #pragma unroll
            for (int ct = 0; ct < 2; ++ct)
                acc[m][ct] = __builtin_amdgcn_mfma_f32_16x16x32_bf16(
                    Af[m], VB[ct][s], acc[m][ct], 0, 0, 0);
    }
    __builtin_amdgcn_s_setprio(0);

    // lsum: combine across g (shfl) then waves (LDS)
    #pragma unroll
    for (int nt = 0; nt < 4; ++nt) {
        float s = lsum[nt];
        s += __shfl_xor(s, 16);
        s += __shfl_xor(s, 32);
        lsum[nt] = s;
    }
    if (l < 16) {
        #pragma unroll
        for (int nt = 0; nt < 4; ++nt) lsum_lds[16 * nt + l][w] = lsum[nt];
    }
    bar_lds();

    const float gam = gamma_p[0];
    for (int m = 0; m < 4; ++m) {
        #pragma unroll
        for (int ct = 0; ct < 2; ++ct)
            #pragma unroll
            for (int r = 0; r < 4; ++r)
                out_lds[4 * g + r][32 * w + 16 * ct + l15] = acc[m][ct][r];
        bar_lds();
        const int qi = tid & 15;
        const int cb2 = tid >> 4;
        float lt = 0.f;
        #pragma unroll
        for (int ww = 0; ww < 8; ++ww) lt += lsum_lds[16 * m + qi][ww];
        const float li = 1.0f / lt;
        #pragma unroll
        for (int p = 0; p < 8; ++p) {
            int c = cb2 + 32 * p;
            size_t ga = ((size_t)(n * CCH + c)) * HWA + q0 + 16 * m + qi;
            out[ga] = gam * out_lds[qi][c] * li + x[ga];
        }
        bar_lds();
    }
}

extern "C" void kernel_launch(void* const* d_in, const int* in_sizes, int n_in,
                              void* d_out, int out_size, void* d_ws, size_t ws_size,
                              hipStream_t stream) {
    const float* x  = (const float*)d_in[0];
    const float* Wq = (const float*)d_in[1];
    const float* bq = (const float*)d_in[2];
    const float* Wk = (const float*)d_in[3];
    const float* bk = (const float*)d_in[4];
    const float* Wv = (const float*)d_in[5];
    const float* bv = (const float*)d_in[6];
    const float* gm = (const float*)d_in[7];
    float* out = (float*)d_out;

    float* bias_all = (float*)d_ws;                               // 320 f
    unsigned short* whi = (unsigned short*)(bias_all + 320);      // 81920
    unsigned short* wlo = whi + 81920;
    unsigned short* qhi = wlo + 81920;                            // 16B-aligned
    unsigned short* qlo = qhi + (size_t)NBATCH * HWA * 32;
    unsigned short* khi = qlo + (size_t)NBATCH * HWA * 32;
    unsigned short* klo = khi + (size_t)NBATCH * HWA * 32;
    unsigned short* vbp = klo + (size_t)NBATCH * HWA * 32;        // 4*256*4096

    hipLaunchKernelGGL(wprep_kernel, dim3(20), dim3(256), 0, stream,
                       Wq, bq, Wk, bk, Wv, bv, whi, wlo, bias_all);
    hipLaunchKernelGGL(qkvgemm_kernel, dim3(512), dim3(256), 0, stream,
                       x, whi, wlo, bias_all, qhi, qlo, khi, klo, vbp);
    hipLaunchKernelGGL(attn_kernel, dim3(256), dim3(512), 0, stream,
                       qhi, qlo, khi, klo, vbp, x, gm, out);
}